// Round 8
// baseline (467.070 us; speedup 1.0000x reference)
//
#include <hip/hip_runtime.h>
#include <math.h>

// Problem constants (from reference setup_inputs)
constexpr int N  = 8;
constexpr int C  = 32;
constexpr int H  = 256;
constexpr int W  = 256;
constexpr int HU = 512;   // upsampled H
constexpr int WU = 512;   // upsampled W
constexpr int HW  = H * W;
constexpr int HWU = HU * WU;

// Round 8 = r7's quad kernel with the wave remapped from a 64x4-px strip to
// a 16x16-px SQUARE tile (8x8 quads). Cross-round fits validate a
// distinct-cache-lines-per-wave cost model (r1 63M touches -> 212us,
// r7 37M -> 163us); the square tile cuts each gather's footprint from
// ~17 rows x ~2 lines (~35 lines/load) to ~8-9 rows x ~1.5 (~13), i.e.
// ~2.7x fewer line-touches. Stores stay dense: 8 lanes x f2 = one aligned
// 64B line per output row. In-wave MLP is a dead end (r7: 1-phase prefetch
// covers 40cy of 400cy latency; deeper -> r6 VGPR/occupancy cliff), so
// latency hiding stays TLP + line reduction.
typedef float f4 __attribute__((ext_vector_type(4)));
typedef float f2 __attribute__((ext_vector_type(2)));
typedef f4 f4u __attribute__((aligned(4)));   // dword-aligned 16B access

// Per-axis decomposition of (grid_sample bilinear) o (upsample2x bilinear):
// a continuous coordinate collapses to a 3-consecutive-texel window of the
// ORIGINAL axis with 3 merged weights. base clamped to [0, n_in-3].
struct Axis {
    int   base;
    float w0, w1, w2;
};

__device__ __forceinline__ Axis make_axis(float coord, int n_in, int n_up) {
    float c0f = floorf(coord);
    float t   = coord - c0f;         // grid_sample frac weight
    int   u0  = (int)c0f;            // upsampled-axis corner a

    float w3_0 = 0.f, w3_1 = 0.f, w3_2 = 0.f;
    int rb = 0;

    #pragma unroll
    for (int k = 0; k < 2; ++k) {
        int   yu    = u0 + k;
        float Wc    = (k == 0) ? (1.0f - t) : t;      // grid_sample corner weight
        bool  valid = (yu >= 0) && (yu < n_up);       // zero-padding mask

        // upsample2x source: s = (yu+0.5)/2 - 0.5, clamped >= 0
        float s  = fmaxf(0.5f * (float)yu - 0.25f, 0.0f);
        int   r0 = (int)s;                            // floor (s >= 0)
        r0 = min(r0, n_in - 1);                       // keep in-bounds for wild yu
        float wu = s - (float)r0;
        int   r1 = min(r0 + 1, n_in - 1);

        float w0 = valid ? Wc * (1.0f - wu) : 0.0f;
        float w1 = valid ? Wc * wu          : 0.0f;

        if (k == 0) rb = min(r0, n_in - 3);           // window base from corner a

        int s0 = min(max(r0 - rb, 0), 2);
        int s1 = min(max(r1 - rb, 0), 2);
        w3_0 += (s0 == 0) ? w0 : 0.0f;
        w3_1 += (s0 == 1) ? w0 : 0.0f;
        w3_2 += (s0 == 2) ? w0 : 0.0f;
        w3_0 += (s1 == 0) ? w1 : 0.0f;
        w3_1 += (s1 == 1) ? w1 : 0.0f;
        w3_2 += (s1 == 2) ? w1 : 0.0f;
    }

    Axis ax;
    ax.base = rb;
    ax.w0 = w3_0; ax.w1 = w3_1; ax.w2 = w3_2;
    return ax;
}

// 4-wide weight vector aligned to a shared window base: e = base - bl in {0,1}
// (e = 2 impossible: bases cap at n-3, so bl = n-4 clamp gives e <= 1).
__device__ __forceinline__ f4 wvec(const Axis& a, int bl) {
    int e = a.base - bl;
    return e ? f4{0.0f, a.w0, a.w1, a.w2} : f4{a.w0, a.w1, a.w2, 0.0f};
}

__global__ __launch_bounds__(128, 4)
void fused_up_affine_sample(const float* __restrict__ x,
                            const float* __restrict__ theta,
                            float* __restrict__ out) {
    int tid  = threadIdx.x;
    int lane = tid & 63;
    int wv   = tid >> 6;                     // wave id in block (0..1)
    int qx   = lane & 7;                     // quad col within 16x16 tile
    int qy   = lane >> 3;                    // quad row within 16x16 tile

    // wave = 16x16-px square tile; block = 2 waves side by side (32x16 px)
    int wo = blockIdx.x * 32 + wv * 16 + qx * 2;   // output cols wo, wo+1
    int ho = blockIdx.y * 16 + qy * 2;             // output rows ho, ho+1
    int n  = blockIdx.z;

    const float* th = theta + n * 6;
    float t0 = th[0], t1 = th[1], t2 = th[2];
    float t3 = th[3], t4 = th[4], t5 = th[5];

    // Axes for the 4 quad pixels (ix AND iy both depend on col and row).
    Axis x00, y00, x01, y01, x10, y10, x11, y11;
    auto pix = [&](int wo_, int ho_, Axis& axx, Axis& axy) {
        float gx = (2.0f * (float)wo_ + 1.0f) * (1.0f / (float)WU) - 1.0f;
        float gy = (2.0f * (float)ho_ + 1.0f) * (1.0f / (float)HU) - 1.0f;
        float ox = t0 * gx + t1 * gy + t2;
        float oy = t3 * gx + t4 * gy + t5;
        float ix = ((ox + 1.0f) * (float)WU - 1.0f) * 0.5f;
        float iy = ((oy + 1.0f) * (float)HU - 1.0f) * 0.5f;
        axx = make_axis(ix, W, WU);
        axy = make_axis(iy, H, HU);
    };
    pix(wo,     ho,     x00, y00);
    pix(wo + 1, ho,     x01, y01);
    pix(wo,     ho + 1, x10, y10);
    pix(wo + 1, ho + 1, x11, y11);

    int bminx = min(min(x00.base, x01.base), min(x10.base, x11.base));
    int bmaxx = max(max(x00.base, x01.base), max(x10.base, x11.base));
    int bminy = min(min(y00.base, y01.base), min(y10.base, y11.base));
    int bmaxy = max(max(y00.base, y01.base), max(y10.base, y11.base));
    bool ok = (bmaxx - bminx <= 1) && (bmaxy - bminy <= 1);

    const float* xn = x   + (size_t)n * (C * HW);
    float*       on = out + (size_t)n * (C * HWU);

    if (!__any(!ok)) {
        // ---- fast path: one 4x4 window serves the whole quad ----
        int blx = min(bminx, W - 4);         // window fully in-image
        int bly = min(bminy, H - 4);

        f4 wx00 = wvec(x00, blx), wx01 = wvec(x01, blx);
        f4 wx10 = wvec(x10, blx), wx11 = wvec(x11, blx);
        f4 wy00 = wvec(y00, bly), wy01 = wvec(y01, bly);
        f4 wy10 = wvec(y10, bly), wy11 = wvec(y11, bly);

        const float* p0 = xn + bly * W + blx;
        float*       ob = on + ho * WU + wo;

        f4 A0, A1, A2, A3, B0, B1, B2, B3;   // named double-buffer (rule #20)
        auto ld = [&](f4& d0, f4& d1, f4& d2, f4& d3, int c) {
            const float* p = p0 + c * HW;
            d0 = *(const f4u*)(p);
            d1 = *(const f4u*)(p + W);
            d2 = *(const f4u*)(p + 2 * W);
            d3 = *(const f4u*)(p + 3 * W);
        };
        auto st = [&](const f4& a0, const f4& a1, const f4& a2, const f4& a3,
                      int c) {
            auto pxv = [&](const f4& wy, const f4& wx) -> float {
                f4 acc = a0 * wy.x + a1 * wy.y + a2 * wy.z + a3 * wy.w;
                return acc.x * wx.x + acc.y * wx.y + acc.z * wx.z + acc.w * wx.w;
            };
            float* po = ob + c * HWU;
            *(f2*)(po)      = f2{pxv(wy00, wx00), pxv(wy01, wx01)};
            *(f2*)(po + WU) = f2{pxv(wy10, wx10), pxv(wy11, wx11)};
        };

        ld(A0, A1, A2, A3, 0);               // prologue
        #pragma unroll
        for (int c = 0; c < C; c += 2) {
            // issue c+1's loads BEFORE consuming c; barrier keeps the
            // scheduler from sinking them below the compute.
            ld(B0, B1, B2, B3, c + 1);       // c+1 <= 31 always (C even)
            __builtin_amdgcn_sched_barrier(0);
            st(A0, A1, A2, A3, c);
            if (c + 2 < C) ld(A0, A1, A2, A3, c + 2);
            __builtin_amdgcn_sched_barrier(0);
            st(B0, B1, B2, B3, c + 1);
        }
    } else {
        // ---- rare fallback (extreme theta): per-pixel 3x3 scalar gather ----
        #pragma unroll
        for (int i = 0; i < 4; ++i) {
            const Axis& axp = (i == 0) ? x00 : (i == 1) ? x01 : (i == 2) ? x10 : x11;
            const Axis& ayp = (i == 0) ? y00 : (i == 1) ? y01 : (i == 2) ? y10 : y11;
            int wo_ = wo + (i & 1);
            int ho_ = ho + (i >> 1);
            const float* pb = xn + ayp.base * W + axp.base;
            float*       po = on + ho_ * WU + wo_;
            for (int c = 0; c < C; ++c) {
                const float* p = pb + c * HW;
                float r0 = p[0        ] * axp.w0 + p[1        ] * axp.w1 + p[2        ] * axp.w2;
                float r1 = p[W        ] * axp.w0 + p[W + 1    ] * axp.w1 + p[W + 2    ] * axp.w2;
                float r2 = p[2 * W    ] * axp.w0 + p[2 * W + 1] * axp.w1 + p[2 * W + 2] * axp.w2;
                po[c * HWU] = ayp.w0 * r0 + ayp.w1 * r1 + ayp.w2 * r2;
            }
        }
    }
}

extern "C" void kernel_launch(void* const* d_in, const int* in_sizes, int n_in,
                              void* d_out, int out_size, void* d_ws, size_t ws_size,
                              hipStream_t stream) {
    const float* x     = (const float*)d_in[0];
    const float* theta = (const float*)d_in[1];
    float*       out   = (float*)d_out;

    dim3 grid(WU / 32, HU / 16, N);   // 16 x 32 x 8 = 4096 blocks, 128 thr
    fused_up_affine_sample<<<grid, 128, 0, stream>>>(x, theta, out);
}

// Round 9
// 400.746 us; speedup vs baseline: 1.1655x; 1.1655x over previous
//
#include <hip/hip_runtime.h>
#include <math.h>

// Problem constants (from reference setup_inputs)
constexpr int N  = 8;
constexpr int C  = 32;
constexpr int H  = 256;
constexpr int W  = 256;
constexpr int HU = 512;   // upsampled H
constexpr int WU = 512;   // upsampled W
constexpr int HW  = H * W;
constexpr int HWU = HU * WU;

// Round 9: wave = 32x8-px tile (16 col-pairs x 4 row-pairs).
// r8 forensics: the 16x16 square wave wrote 64B per row per store = HALF a
// 128B cache line -> TCC read-modify-write (WRITE_SIZE +23%, FETCH 3x).
// Constraints now: (a) stores must cover full 128B lines per instruction
// => wave >= 32px wide (16 lanes x f2, 128B-aligned); (b) gather footprint
// as square as possible (line-touch model: r1 63M->212us, r7 37M->163us).
// 32x8 satisfies both: stores = exactly one aligned 128B line per row per
// 16-lane group; gather spans ~(32|t0|+8|t1|)/2 ~ 10 px each axis.
typedef float f4 __attribute__((ext_vector_type(4)));
typedef float f2 __attribute__((ext_vector_type(2)));
typedef f4 f4u __attribute__((aligned(4)));   // dword-aligned 16B access

// Per-axis decomposition of (grid_sample bilinear) o (upsample2x bilinear):
// a continuous coordinate collapses to a 3-consecutive-texel window of the
// ORIGINAL axis with 3 merged weights. base clamped to [0, n_in-3].
struct Axis {
    int   base;
    float w0, w1, w2;
};

__device__ __forceinline__ Axis make_axis(float coord, int n_in, int n_up) {
    float c0f = floorf(coord);
    float t   = coord - c0f;         // grid_sample frac weight
    int   u0  = (int)c0f;            // upsampled-axis corner a

    float w3_0 = 0.f, w3_1 = 0.f, w3_2 = 0.f;
    int rb = 0;

    #pragma unroll
    for (int k = 0; k < 2; ++k) {
        int   yu    = u0 + k;
        float Wc    = (k == 0) ? (1.0f - t) : t;      // grid_sample corner weight
        bool  valid = (yu >= 0) && (yu < n_up);       // zero-padding mask

        // upsample2x source: s = (yu+0.5)/2 - 0.5, clamped >= 0
        float s  = fmaxf(0.5f * (float)yu - 0.25f, 0.0f);
        int   r0 = (int)s;                            // floor (s >= 0)
        r0 = min(r0, n_in - 1);                       // keep in-bounds for wild yu
        float wu = s - (float)r0;
        int   r1 = min(r0 + 1, n_in - 1);

        float w0 = valid ? Wc * (1.0f - wu) : 0.0f;
        float w1 = valid ? Wc * wu          : 0.0f;

        if (k == 0) rb = min(r0, n_in - 3);           // window base from corner a

        int s0 = min(max(r0 - rb, 0), 2);
        int s1 = min(max(r1 - rb, 0), 2);
        w3_0 += (s0 == 0) ? w0 : 0.0f;
        w3_1 += (s0 == 1) ? w0 : 0.0f;
        w3_2 += (s0 == 2) ? w0 : 0.0f;
        w3_0 += (s1 == 0) ? w1 : 0.0f;
        w3_1 += (s1 == 1) ? w1 : 0.0f;
        w3_2 += (s1 == 2) ? w1 : 0.0f;
    }

    Axis ax;
    ax.base = rb;
    ax.w0 = w3_0; ax.w1 = w3_1; ax.w2 = w3_2;
    return ax;
}

// 4-wide weight vector aligned to a shared window base: e = base - bl in {0,1}
// (e = 2 impossible: bases cap at n-3, so bl = n-4 clamp gives e <= 1).
__device__ __forceinline__ f4 wvec(const Axis& a, int bl) {
    int e = a.base - bl;
    return e ? f4{0.0f, a.w0, a.w1, a.w2} : f4{a.w0, a.w1, a.w2, 0.0f};
}

__global__ __launch_bounds__(128, 4)
void fused_up_affine_sample(const float* __restrict__ x,
                            const float* __restrict__ theta,
                            float* __restrict__ out) {
    int tid  = threadIdx.x;
    int lane = tid & 63;
    int wv   = tid >> 6;                     // wave id in block (0..1)
    int qx   = lane & 15;                    // quad col within 32x8 tile
    int qy   = lane >> 4;                    // quad row within 32x8 tile (0..3)

    // wave = 32x8-px tile; block = 2 waves stacked vertically (32x16 px)
    int wo = blockIdx.x * 32 + qx * 2;               // output cols wo, wo+1
    int ho = blockIdx.y * 16 + wv * 8 + qy * 2;      // output rows ho, ho+1
    int n  = blockIdx.z;

    const float* th = theta + n * 6;
    float t0 = th[0], t1 = th[1], t2 = th[2];
    float t3 = th[3], t4 = th[4], t5 = th[5];

    // Axes for the 4 quad pixels (ix AND iy both depend on col and row).
    Axis x00, y00, x01, y01, x10, y10, x11, y11;
    auto pix = [&](int wo_, int ho_, Axis& axx, Axis& axy) {
        float gx = (2.0f * (float)wo_ + 1.0f) * (1.0f / (float)WU) - 1.0f;
        float gy = (2.0f * (float)ho_ + 1.0f) * (1.0f / (float)HU) - 1.0f;
        float ox = t0 * gx + t1 * gy + t2;
        float oy = t3 * gx + t4 * gy + t5;
        float ix = ((ox + 1.0f) * (float)WU - 1.0f) * 0.5f;
        float iy = ((oy + 1.0f) * (float)HU - 1.0f) * 0.5f;
        axx = make_axis(ix, W, WU);
        axy = make_axis(iy, H, HU);
    };
    pix(wo,     ho,     x00, y00);
    pix(wo + 1, ho,     x01, y01);
    pix(wo,     ho + 1, x10, y10);
    pix(wo + 1, ho + 1, x11, y11);

    int bminx = min(min(x00.base, x01.base), min(x10.base, x11.base));
    int bmaxx = max(max(x00.base, x01.base), max(x10.base, x11.base));
    int bminy = min(min(y00.base, y01.base), min(y10.base, y11.base));
    int bmaxy = max(max(y00.base, y01.base), max(y10.base, y11.base));
    bool ok = (bmaxx - bminx <= 1) && (bmaxy - bminy <= 1);

    const float* xn = x   + (size_t)n * (C * HW);
    float*       on = out + (size_t)n * (C * HWU);

    if (!__any(!ok)) {
        // ---- fast path: one 4x4 window serves the whole quad ----
        int blx = min(bminx, W - 4);         // window fully in-image
        int bly = min(bminy, H - 4);

        f4 wx00 = wvec(x00, blx), wx01 = wvec(x01, blx);
        f4 wx10 = wvec(x10, blx), wx11 = wvec(x11, blx);
        f4 wy00 = wvec(y00, bly), wy01 = wvec(y01, bly);
        f4 wy10 = wvec(y10, bly), wy11 = wvec(y11, bly);

        const float* p0 = xn + bly * W + blx;
        float*       ob = on + ho * WU + wo;

        f4 A0, A1, A2, A3, B0, B1, B2, B3;   // named double-buffer (rule #20)
        auto ld = [&](f4& d0, f4& d1, f4& d2, f4& d3, int c) {
            const float* p = p0 + c * HW;
            d0 = *(const f4u*)(p);
            d1 = *(const f4u*)(p + W);
            d2 = *(const f4u*)(p + 2 * W);
            d3 = *(const f4u*)(p + 3 * W);
        };
        auto st = [&](const f4& a0, const f4& a1, const f4& a2, const f4& a3,
                      int c) {
            auto pxv = [&](const f4& wy, const f4& wx) -> float {
                f4 acc = a0 * wy.x + a1 * wy.y + a2 * wy.z + a3 * wy.w;
                return acc.x * wx.x + acc.y * wx.y + acc.z * wx.z + acc.w * wx.w;
            };
            float* po = ob + c * HWU;
            *(f2*)(po)      = f2{pxv(wy00, wx00), pxv(wy01, wx01)};
            *(f2*)(po + WU) = f2{pxv(wy10, wx10), pxv(wy11, wx11)};
        };

        ld(A0, A1, A2, A3, 0);               // prologue
        #pragma unroll
        for (int c = 0; c < C; c += 2) {
            // issue c+1's loads BEFORE consuming c; barrier keeps the
            // scheduler from sinking them below the compute.
            ld(B0, B1, B2, B3, c + 1);       // c+1 <= 31 always (C even)
            __builtin_amdgcn_sched_barrier(0);
            st(A0, A1, A2, A3, c);
            if (c + 2 < C) ld(A0, A1, A2, A3, c + 2);
            __builtin_amdgcn_sched_barrier(0);
            st(B0, B1, B2, B3, c + 1);
        }
    } else {
        // ---- rare fallback (extreme theta): per-pixel 3x3 scalar gather ----
        #pragma unroll
        for (int i = 0; i < 4; ++i) {
            const Axis& axp = (i == 0) ? x00 : (i == 1) ? x01 : (i == 2) ? x10 : x11;
            const Axis& ayp = (i == 0) ? y00 : (i == 1) ? y01 : (i == 2) ? y10 : y11;
            int wo_ = wo + (i & 1);
            int ho_ = ho + (i >> 1);
            const float* pb = xn + ayp.base * W + axp.base;
            float*       po = on + ho_ * WU + wo_;
            for (int c = 0; c < C; ++c) {
                const float* p = pb + c * HW;
                float r0 = p[0        ] * axp.w0 + p[1        ] * axp.w1 + p[2        ] * axp.w2;
                float r1 = p[W        ] * axp.w0 + p[W + 1    ] * axp.w1 + p[W + 2    ] * axp.w2;
                float r2 = p[2 * W    ] * axp.w0 + p[2 * W + 1] * axp.w1 + p[2 * W + 2] * axp.w2;
                po[c * HWU] = ayp.w0 * r0 + ayp.w1 * r1 + ayp.w2 * r2;
            }
        }
    }
}

extern "C" void kernel_launch(void* const* d_in, const int* in_sizes, int n_in,
                              void* d_out, int out_size, void* d_ws, size_t ws_size,
                              hipStream_t stream) {
    const float* x     = (const float*)d_in[0];
    const float* theta = (const float*)d_in[1];
    float*       out   = (float*)d_out;

    dim3 grid(WU / 32, HU / 16, N);   // 16 x 32 x 8 = 4096 blocks, 128 thr
    fused_up_affine_sample<<<grid, 128, 0, stream>>>(x, theta, out);
}